// Round 1
// baseline (70.367 us; speedup 1.0000x reference)
//
#include <hip/hip_runtime.h>
#include <math.h>

// DeepFeatureLoss: B=2, N=4096, D=32, fp32.
// out[0..1] = ce_loss[b], out[2..3] = reg_loss[b].
//
// ce_i = log(s_f) - t/s_p  with (max fixed at 0, both dists <= 0):
//   s_p = sum_j exp(pd_ij), t = sum_j exp(pd_ij)*fd_ij, s_f = sum_j exp(fd_ij)
// pd via direct coordinate diff (accuracy at 1/sigma=200 scale),
// fd via 2*f1.f2 - n1 - n2 (norms precomputed).
//
// ws layout (floats): [0, 8192) n2 ; [8192, 8192+32*3*8192) chunk partials
//   partials[c][comp][row], comp in {s_p, t, s_f}.  ~3.1 MB total.

#define NPTS 4096
#define BATCH 2
#define DF 32
#define CHUNK 128
#define NCHUNK (NPTS / CHUNK)          // 32
#define ROWS_TOT (BATCH * NPTS)        // 8192

static __device__ __forceinline__ float inv_sigma() { return 1.0f / 0.005f; }

__global__ void k0_norms(const float* __restrict__ fea2,
                         float* __restrict__ n2,
                         float* __restrict__ out) {
    int r = blockIdx.x * 256 + threadIdx.x;      // 0..8191
    if (r < 4) out[r] = 0.0f;                    // zero outputs each call
    const float4* f = (const float4*)(fea2 + (size_t)r * DF);
    float s = 0.0f;
#pragma unroll
    for (int q = 0; q < 8; ++q) {
        float4 v = f[q];
        s += v.x * v.x + v.y * v.y + v.z * v.z + v.w * v.w;
    }
    n2[r] = s;
}

__launch_bounds__(256)
__global__ void k1_main(const float* __restrict__ pts,
                        const float* __restrict__ f1g,
                        const float* __restrict__ f2g,
                        const float* __restrict__ n2g,
                        float* __restrict__ part) {
    __shared__ float sF2[CHUNK * DF];     // 16 KB
    __shared__ float4 sP2[CHUNK];         //  2 KB: (x,y,z)*inv_sigma, n2

    const int tid = threadIdx.x;
    const int r   = blockIdx.x * 256 + tid;    // global row (256 | 4096 -> b uniform)
    const int b   = r >> 12;
    const int j0  = blockIdx.y * CHUNK;
    const int jrow0 = b * NPTS + j0;

    // ---- stage f2 chunk (coalesced) ----
    const float4* g4 = (const float4*)(f2g + (size_t)jrow0 * DF);
    float4* s4 = (float4*)sF2;
#pragma unroll
    for (int k = 0; k < (CHUNK * DF / 4) / 256; ++k)   // 4 iters
        s4[tid + k * 256] = g4[tid + k * 256];
    if (tid < CHUNK) {
        const float* pp = pts + (size_t)(jrow0 + tid) * 3;
        sP2[tid] = make_float4(pp[0] * inv_sigma(), pp[1] * inv_sigma(),
                               pp[2] * inv_sigma(), n2g[jrow0 + tid]);
    }

    // ---- own row in registers ----
    float4 f1q[8];
    const float4* f1v = (const float4*)(f1g + (size_t)r * DF);
#pragma unroll
    for (int q = 0; q < 8; ++q) f1q[q] = f1v[q];
    float n1 = 0.0f;
#pragma unroll
    for (int q = 0; q < 8; ++q) {
        float4 v = f1q[q];
        n1 += v.x * v.x + v.y * v.y + v.z * v.z + v.w * v.w;
    }
    const float* p1p = pts + (size_t)r * 3;
    const float p1x = p1p[0] * inv_sigma();
    const float p1y = p1p[1] * inv_sigma();
    const float p1z = p1p[2] * inv_sigma();

    __syncthreads();

    float sp = 0.0f, tacc = 0.0f, sf = 0.0f;
    for (int jj = 0; jj < CHUNK; ++jj) {
        const float4 pn = sP2[jj];
        const float4* fv = (const float4*)(sF2 + jj * DF);
        float d0 = 0.f, d1 = 0.f, d2 = 0.f, d3 = 0.f;
#pragma unroll
        for (int q = 0; q < 8; ++q) {
            float4 v = fv[q];
            d0 = fmaf(f1q[q].x, v.x, d0);
            d1 = fmaf(f1q[q].y, v.y, d1);
            d2 = fmaf(f1q[q].z, v.z, d2);
            d3 = fmaf(f1q[q].w, v.w, d3);
        }
        const float dot = (d0 + d1) + (d2 + d3);
        const float dx = p1x - pn.x, dy = p1y - pn.y, dz = p1z - pn.z;
        const float s  = fmaf(dx, dx, fmaf(dy, dy, dz * dz));
        const float ep = __expf(-s);
        const float fd = fmaf(2.0f, dot, -(n1 + pn.w));
        const float ef = __expf(fd);
        sp += ep;
        tacc = fmaf(ep, fd, tacc);
        sf += ef;
    }

    float* P = part + (size_t)blockIdx.y * 3 * ROWS_TOT;
    P[r]                = sp;     // coalesced per component plane
    P[ROWS_TOT + r]     = tacc;
    P[2 * ROWS_TOT + r] = sf;
}

__global__ void k2_final(const float* __restrict__ part,
                         const float* __restrict__ f1g,
                         const float* __restrict__ f2g,
                         const float* __restrict__ wg,
                         float* __restrict__ out) {
    __shared__ float redc[4], redr[4];
    const int tid = threadIdx.x;
    const int r = blockIdx.x * 256 + tid;
    const int b = r >> 12;

    float sp = 0.f, tp = 0.f, sf = 0.f;
#pragma unroll 4
    for (int c = 0; c < NCHUNK; ++c) {
        const float* P = part + (size_t)c * 3 * ROWS_TOT;
        sp += P[r];
        tp += P[ROWS_TOT + r];
        sf += P[2 * ROWS_TOT + r];
    }
    const float ce = logf(sf) - tp / sp;
    float contrib = wg[r] * ce;

    // reg: sum over channels 3..31 of f1^2 + f2^2
    const float4* a4 = (const float4*)(f1g + (size_t)r * DF);
    const float4* b4 = (const float4*)(f2g + (size_t)r * DF);
    float rr = 0.0f;
    {
        float4 a0 = a4[0], b0 = b4[0];
        rr = a0.w * a0.w + b0.w * b0.w;  // channel 3 only from first quad
    }
#pragma unroll
    for (int q = 1; q < 8; ++q) {
        float4 av = a4[q], bv = b4[q];
        rr += av.x * av.x + av.y * av.y + av.z * av.z + av.w * av.w;
        rr += bv.x * bv.x + bv.y * bv.y + bv.z * bv.z + bv.w * bv.w;
    }

    // wave (64) reduce
#pragma unroll
    for (int off = 32; off > 0; off >>= 1) {
        contrib += __shfl_down(contrib, off);
        rr      += __shfl_down(rr, off);
    }
    const int wave = tid >> 6, lane = tid & 63;
    if (lane == 0) { redc[wave] = contrib; redr[wave] = rr; }
    __syncthreads();
    if (tid == 0) {
        float c = redc[0] + redc[1] + redc[2] + redc[3];
        float rs = redr[0] + redr[1] + redr[2] + redr[3];
        atomicAdd(&out[b], c);
        atomicAdd(&out[2 + b], rs * (1.0f / (29.0f * (float)NPTS)));
    }
}

extern "C" void kernel_launch(void* const* d_in, const int* in_sizes, int n_in,
                              void* d_out, int out_size, void* d_ws, size_t ws_size,
                              hipStream_t stream) {
    const float* pts = (const float*)d_in[0];
    const float* f1  = (const float*)d_in[1];
    const float* f2  = (const float*)d_in[2];
    const float* wg  = (const float*)d_in[3];
    float* out = (float*)d_out;

    float* ws   = (float*)d_ws;
    float* n2   = ws;                    // 8192 floats
    float* part = ws + ROWS_TOT;         // 32*3*8192 floats

    k0_norms<<<ROWS_TOT / 256, 256, 0, stream>>>(f2, n2, out);
    k1_main<<<dim3(ROWS_TOT / 256, NCHUNK), 256, 0, stream>>>(pts, f1, f2, n2, part);
    k2_final<<<ROWS_TOT / 256, 256, 0, stream>>>(part, f1, f2, wg, out);
}

// Round 2
// 35.927 us; speedup vs baseline: 1.9586x; 1.9586x over previous
//
#include <hip/hip_runtime.h>
#include <math.h>

// DeepFeatureLoss: B=2, N=4096, D=32, fp32 in/out.
// out[0..1] = ce_loss[b], out[2..3] = reg_loss[b].
//
// ce_i = log(s_f) - t/s_p   (softmax max pinned at 0; both dists <= 0):
//   s_p = sum_j exp(pd_ij), t = sum_j exp(pd_ij)*fd_ij, s_f = sum_j exp(fd_ij)
// pd: direct coordinate diff in fp32 (1/sigma=200 -> expansion inaccurate).
// fd = 2*(f1.f2) - n1 - n2 : dot via mfma_f32_16x16x32_f16 (K=32=D, one
// MFMA per 16x16 tile), norms in fp32.
//
// Fragment layouts (cdna4_isa / verified m89 family):
//   A[row][k]: row = lane&15, k = (lane>>4)*8 + i
//   B[k][col]: col = lane&15, k = (lane>>4)*8 + i
//   C[row][col]: col = lane&15, row = (lane>>4)*4 + reg
//
// ws (floats): pp1 [0,32768) ; pp2 [32768,65536) ; f2 f16 frags
// [65536,196608) ; partials [196608, 196608+16*3*8192).  ~2.3 MB.

#define NPTS 4096
#define BATCH 2
#define DF 32
#define ROWS_TOT (BATCH * NPTS)   // 8192
#define NCHUNK 16                  // j-chunks of 256 (16 j-tiles)

typedef _Float16 half8 __attribute__((ext_vector_type(8)));
typedef float floatx4 __attribute__((ext_vector_type(4)));

static __device__ __forceinline__ float inv_sigma() { return 200.0f; }

// ---- k0: pack pp1=(p/s,n1), pp2=(p/s,n2), f2 -> f16 fragment order ----
__global__ void k0_prep(const float* __restrict__ pts,
                        const float* __restrict__ f1g,
                        const float* __restrict__ f2g,
                        float* __restrict__ pp1, float* __restrict__ pp2,
                        _Float16* __restrict__ frag, float* __restrict__ out) {
    const int r = blockIdx.x * 256 + threadIdx.x;   // global row 0..8191
    if (r < 4) out[r] = 0.0f;
    const int b = r >> 12, local = r & (NPTS - 1);
    const int jt = (b << 8) + (local >> 4);          // global j-tile id
    const int c  = local & 15;                       // col within tile

    const float4* f2v = (const float4*)(f2g + (size_t)r * DF);
    float vals[32];
    float n2 = 0.0f;
#pragma unroll
    for (int q = 0; q < 8; ++q) {
        float4 v = f2v[q];
        vals[4*q] = v.x; vals[4*q+1] = v.y; vals[4*q+2] = v.z; vals[4*q+3] = v.w;
        n2 += v.x*v.x + v.y*v.y + v.z*v.z + v.w*v.w;
    }
    half8* fv = (half8*)frag;
#pragma unroll
    for (int kb = 0; kb < 4; ++kb) {                 // slot = c*4 + kb
        half8 h;
#pragma unroll
        for (int i = 0; i < 8; ++i) h[i] = (_Float16)vals[kb*8 + i];
        fv[(size_t)jt*64 + c*4 + kb] = h;
    }
    const float4* f1v = (const float4*)(f1g + (size_t)r * DF);
    float n1 = 0.0f;
#pragma unroll
    for (int q = 0; q < 8; ++q) {
        float4 v = f1v[q];
        n1 += v.x*v.x + v.y*v.y + v.z*v.z + v.w*v.w;
    }
    const float* pp = pts + (size_t)r * 3;
    const float px = pp[0]*inv_sigma(), py = pp[1]*inv_sigma(), pz = pp[2]*inv_sigma();
    ((float4*)pp1)[r] = make_float4(px, py, pz, n1);
    ((float4*)pp2)[r] = make_float4(px, py, pz, n2);
}

// ---- k1: MFMA dots + fused softmax-sum epilogue, no LDS ----
__launch_bounds__(256)
__global__ void k1_main(const float* __restrict__ f1g,
                        const float* __restrict__ pp1,
                        const float* __restrict__ pp2,
                        const _Float16* __restrict__ frag,
                        float* __restrict__ part) {
    const int tid = threadIdx.x;
    const int l = tid & 63, wv = tid >> 6;
    const int chunk = blockIdx.x & 15;               // 4 waves share chunk (L1 reuse)
    const int i_tile = (blockIdx.x >> 4) * 4 + wv;   // 0..511
    const int b = i_tile >> 8;
    const int i0g = b * NPTS + (i_tile & 255) * 16;  // global row base of tile
    const int lr = l & 15, lk = l >> 4;

    // A fragment: f1[i0g+lr][lk*8 .. lk*8+7] -> f16
    const float* arow = f1g + (size_t)(i0g + lr) * DF + lk * 8;
    const float4 a0 = *(const float4*)arow;
    const float4 a1 = *(const float4*)(arow + 4);
    half8 afrag;
    afrag[0]=(_Float16)a0.x; afrag[1]=(_Float16)a0.y; afrag[2]=(_Float16)a0.z; afrag[3]=(_Float16)a0.w;
    afrag[4]=(_Float16)a1.x; afrag[5]=(_Float16)a1.y; afrag[6]=(_Float16)a1.z; afrag[7]=(_Float16)a1.w;

    // this lane's 4 output rows: i0g + lk*4 + r
    const int rbase = i0g + lk * 4;
    const float4 q0 = ((const float4*)pp1)[rbase + 0];
    const float4 q1 = ((const float4*)pp1)[rbase + 1];
    const float4 q2 = ((const float4*)pp1)[rbase + 2];
    const float4 q3 = ((const float4*)pp1)[rbase + 3];

    float sp[4] = {0,0,0,0}, tA[4] = {0,0,0,0}, sf[4] = {0,0,0,0};
    const half8* fragv = (const half8*)frag;
    const int jt0 = b * 256 + chunk * 16;
    const int j0g0 = b * NPTS + chunk * 256 + lr;
    const floatx4 zero = {0.f, 0.f, 0.f, 0.f};

#pragma unroll 4
    for (int t = 0; t < 16; ++t) {
        const half8 bfrag = fragv[(size_t)(jt0 + t) * 64 + lr * 4 + lk];
        const float4 pw = ((const float4*)pp2)[j0g0 + t * 16];
        floatx4 cc = __builtin_amdgcn_mfma_f32_16x16x32_f16(afrag, bfrag, zero, 0, 0, 0);
#pragma unroll
        for (int r2 = 0; r2 < 4; ++r2) {
            const float4 q = (r2 == 0) ? q0 : (r2 == 1) ? q1 : (r2 == 2) ? q2 : q3;
            const float fd = fmaf(2.0f, cc[r2], -(q.w + pw.w));
            const float dx = q.x - pw.x, dy = q.y - pw.y, dz = q.z - pw.z;
            const float s  = fmaf(dx, dx, fmaf(dy, dy, dz * dz));
            const float ep = __expf(-s);
            const float ef = __expf(fd);
            sp[r2] += ep;
            tA[r2] = fmaf(ep, fd, tA[r2]);
            sf[r2] += ef;
        }
    }

    // reduce over the 16 columns (lane bits 0..3)
#pragma unroll
    for (int m = 1; m < 16; m <<= 1) {
#pragma unroll
        for (int r2 = 0; r2 < 4; ++r2) {
            sp[r2] += __shfl_xor(sp[r2], m);
            tA[r2] += __shfl_xor(tA[r2], m);
            sf[r2] += __shfl_xor(sf[r2], m);
        }
    }
    if (lr == 0) {
        float* P = part + (size_t)chunk * 3 * ROWS_TOT;
        *(float4*)(P + rbase)                = make_float4(sp[0], sp[1], sp[2], sp[3]);
        *(float4*)(P + ROWS_TOT + rbase)     = make_float4(tA[0], tA[1], tA[2], tA[3]);
        *(float4*)(P + 2 * ROWS_TOT + rbase) = make_float4(sf[0], sf[1], sf[2], sf[3]);
    }
}

// ---- k2: combine chunk partials, ce + reg reduction ----
__global__ void k2_final(const float* __restrict__ part,
                         const float* __restrict__ f1g,
                         const float* __restrict__ f2g,
                         const float* __restrict__ wg,
                         float* __restrict__ out) {
    __shared__ float redc[4], redr[4];
    const int tid = threadIdx.x;
    const int r = blockIdx.x * 256 + tid;
    const int b = r >> 12;

    float sp = 0.f, tp = 0.f, sf = 0.f;
#pragma unroll 4
    for (int c = 0; c < NCHUNK; ++c) {
        const float* P = part + (size_t)c * 3 * ROWS_TOT;
        sp += P[r];
        tp += P[ROWS_TOT + r];
        sf += P[2 * ROWS_TOT + r];
    }
    const float ce = logf(sf) - tp / sp;
    float contrib = wg[r] * ce;

    const float4* a4 = (const float4*)(f1g + (size_t)r * DF);
    const float4* b4 = (const float4*)(f2g + (size_t)r * DF);
    float rr;
    {
        float4 a0 = a4[0], b0 = b4[0];
        rr = a0.w * a0.w + b0.w * b0.w;   // channel 3 from first quad
    }
#pragma unroll
    for (int q = 1; q < 8; ++q) {
        float4 av = a4[q], bv = b4[q];
        rr += av.x*av.x + av.y*av.y + av.z*av.z + av.w*av.w;
        rr += bv.x*bv.x + bv.y*bv.y + bv.z*bv.z + bv.w*bv.w;
    }

#pragma unroll
    for (int off = 32; off > 0; off >>= 1) {
        contrib += __shfl_down(contrib, off);
        rr      += __shfl_down(rr, off);
    }
    const int wave = tid >> 6, lane = tid & 63;
    if (lane == 0) { redc[wave] = contrib; redr[wave] = rr; }
    __syncthreads();
    if (tid == 0) {
        atomicAdd(&out[b],     redc[0] + redc[1] + redc[2] + redc[3]);
        atomicAdd(&out[2 + b], (redr[0] + redr[1] + redr[2] + redr[3])
                               * (1.0f / (29.0f * (float)NPTS)));
    }
}

extern "C" void kernel_launch(void* const* d_in, const int* in_sizes, int n_in,
                              void* d_out, int out_size, void* d_ws, size_t ws_size,
                              hipStream_t stream) {
    const float* pts = (const float*)d_in[0];
    const float* f1  = (const float*)d_in[1];
    const float* f2  = (const float*)d_in[2];
    const float* wg  = (const float*)d_in[3];
    float* out = (float*)d_out;

    float* ws = (float*)d_ws;
    float*     pp1  = ws;                       // 32768 floats
    float*     pp2  = ws + 32768;               // 32768 floats
    _Float16*  frag = (_Float16*)(ws + 65536);  // 262144 halves (131072 floats)
    float*     part = ws + 196608;              // 16*3*8192 floats

    k0_prep<<<ROWS_TOT / 256, 256, 0, stream>>>(pts, f1, f2, pp1, pp2, frag, out);
    k1_main<<<dim3((ROWS_TOT / 16 / 4) * NCHUNK), 256, 0, stream>>>(f1, pp1, pp2, frag, part);
    k2_final<<<ROWS_TOT / 256, 256, 0, stream>>>(part, f1, f2, wg, out);
}